// Round 12
// baseline (183.653 us; speedup 1.0000x reference)
//
#include <hip/hip_runtime.h>
#include <hip/hip_bf16.h>

#define BATCH 16384

typedef __attribute__((ext_vector_type(8))) short short8;
typedef __attribute__((ext_vector_type(4))) short short4v;
typedef __attribute__((ext_vector_type(2))) short sshort2;
typedef __attribute__((ext_vector_type(8))) unsigned short ushort8;
typedef __attribute__((ext_vector_type(4))) unsigned short ushort4v;
typedef __attribute__((ext_vector_type(4))) float float4v;

// ---- d_ws layout (bytes) ----
// frags: A1 [63][th:4][lane:64][32B] | A2 [63][lane:64][tg:4][th:4][8B] | A3 [63][lane:64][tg:4][8B]
#define FR_A1      0u
#define FR_A2      516096u
#define FR_A3      1032192u
#define FR_SIZE    1161216u
#define XBF_SIZE   2097152u     // x as bf16 [16384][64]

__device__ __forceinline__ unsigned int packbf2(float a, float b) {
#if __has_builtin(__builtin_amdgcn_cvt_pk_bf16_f32)
    typedef __attribute__((ext_vector_type(2))) __bf16 bf2_t;
    union { bf2_t h; unsigned int u; } v;
    v.h = __builtin_amdgcn_cvt_pk_bf16_f32(a, b);
    return v.u;
#else
    union { __hip_bfloat162 h; unsigned int u; } v;
    v.h = __float22bfloat162_rn(make_float2(a, b));
    return v.u;
#endif
}
// packed relu on two bf16 halves: i16 max with 0 (valid: bf16 neg <=> i16 neg; no NaNs here)
__device__ __forceinline__ unsigned int relu_pk(unsigned int u) {
#if __has_builtin(__builtin_elementwise_max)
    union { sshort2 s; unsigned int w; } v; v.w = u;
    v.s = __builtin_elementwise_max(v.s, (sshort2)0);
    return v.w;
#else
    unsigned int lo = (u & 0x8000u) ? 0u : (u & 0xFFFFu);
    unsigned int hi = (u & 0x80000000u) ? 0u : (u & 0xFFFF0000u);
    return lo | hi;
#endif
}
__device__ __forceinline__ unsigned int cvt_relu(float a, float b) {
    return relu_pk(packbf2(a, b));
}
__device__ __forceinline__ unsigned short f2bf(float a) {
    union { __hip_bfloat16 h; unsigned short u; } v;
    v.h = __float2bfloat16(a);
    return v.u;
}

// ---------------- setup: fused weight-fragment prep (blocks 0..62) + x cvt (blocks 63..318) ----------------
__global__ __launch_bounds__(256) void setup_kernel(
    const float* __restrict__ x,
    const float* __restrict__ W1,  // [63,64,64] [d][h]
    const float* __restrict__ W2,  // [63,64,64] [h][g]
    const float* __restrict__ W3,  // [63,64,2]  [g][o]
    char* __restrict__ frag,
    char* __restrict__ xbf)        // may be null when grid==63
{
    const int b = blockIdx.x;
    const int t = threadIdx.x;

    if (b >= 63) {
        const int idx = (b - 63) * 256 + t;          // 0..65535, 16 floats each
        const float* xp = x + (size_t)idx * 16;
        char* dst = xbf + (size_t)idx * 32;
        #pragma unroll
        for (int h = 0; h < 2; ++h) {
            float4v f0 = *(const float4v*)(xp + h * 8);
            float4v f1 = *(const float4v*)(xp + h * 8 + 4);
            union { ushort8 s; unsigned int u[4]; } p;
            p.u[0] = packbf2(f0[0], f0[1]);
            p.u[1] = packbf2(f0[2], f0[3]);
            p.u[2] = packbf2(f1[0], f1[1]);
            p.u[3] = packbf2(f1[2], f1[3]);
            *(ushort8*)(dst + h * 16) = p.s;
        }
        return;
    }

    const int kn   = b;
    const int net  = kn + 1;
    const int lane = t & 63;
    const int grp  = t >> 6;       // th (A1) / tg (A2, A3)
    const int lq   = lane & 15;
    const int quad = lane >> 4;

    // A1: A[m=h=lq+16*th][k=d=quad*8+j (a10) / +32 (a11)], masked d < net
    {
        const int h = lq + 16 * grp;
        ushort8 a10, a11;
        #pragma unroll
        for (int j = 0; j < 8; ++j) {
            const int d0 = quad * 8 + j;
            const int d1 = d0 + 32;
            a10[j] = (d0 < net) ? f2bf(W1[kn * 4096 + d0 * 64 + h]) : (unsigned short)0;
            a11[j] = (d1 < net) ? f2bf(W1[kn * 4096 + d1 * 64 + h]) : (unsigned short)0;
        }
        char* dst = frag + FR_A1 + kn * 8192 + grp * 2048 + lane * 32;
        *(ushort8*)(dst)      = a10;
        *(ushort8*)(dst + 16) = a11;
    }

    // A2 (_1k): A[m=g=lq+16*tg][k=h=quad*4+16*th+i]
    {
        const int g = lq + 16 * grp;
        #pragma unroll
        for (int th = 0; th < 4; ++th) {
            ushort4v v;
            #pragma unroll
            for (int i = 0; i < 4; ++i) {
                const int h = quad * 4 + 16 * th + i;
                v[i] = f2bf(W2[kn * 4096 + h * 64 + g]);
            }
            *(ushort4v*)(frag + FR_A2 + kn * 8192 + lane * 128 + grp * 32 + th * 8) = v;
        }
    }

    // A3 (_1k): A[m=o=lq (0/1)][k=g=quad*4+16*tg+i], rows >= 2 zero
    {
        ushort4v v;
        #pragma unroll
        for (int i = 0; i < 4; ++i) {
            const int g = quad * 4 + 16 * grp + i;
            v[i] = (lq < 2) ? f2bf(W3[kn * 128 + g * 2 + lq]) : (unsigned short)0;
        }
        *(ushort4v*)(frag + FR_A3 + kn * 2048 + lane * 32 + grp * 8) = v;
    }
}

// ---------------- main: block = 256-row chunk x 4-net group; 64 rows/wave (tm=4); 16 waves/CU ----------------
// grid 1024: chunk = bi & 63, group g = bi >> 6 (0..15). Line-sharing groups differ by 64 in bi -> same XCD.
template <bool XBF>
__global__ __launch_bounds__(256, 4) void arnet_main4(
    const float* __restrict__ x,
    const char* __restrict__ xbf,
    const char* __restrict__ frag,
    const float* __restrict__ w0, const float* __restrict__ b0,
    const float* __restrict__ v0, const float* __restrict__ c0,
    const float* __restrict__ B1, const float* __restrict__ B2,
    const float* __restrict__ B3,
    float* __restrict__ out)
{
    const int bi    = blockIdx.x;        // 0..1023
    const int chunk = bi & 63;           // 256-row chunk
    const int g     = bi >> 6;           // net group: nets 4g .. 4g+3
    const int t     = threadIdx.x;

    const int lane = t & 63;
    const int w    = t >> 6;
    const int lq   = lane & 15;
    const int quad = lane >> 4;

    __shared__ float sOut[2][256][5];    // pad 5: write conflict-free; 10 KB

    const int rowbase = chunk * 256 + w * 64;

    // ---- load x fragments ONCE (64 rows/wave), reuse for all 4 nets ----
    short8 xf[4][2];
    #pragma unroll
    for (int tm = 0; tm < 4; ++tm) {
        if (XBF) {
            const char* base = xbf + (size_t)(rowbase + 16 * tm + lq) * 128 + quad * 16;
            xf[tm][0] = *(const short8*)(base);
            xf[tm][1] = *(const short8*)(base + 64);
        } else {
            const float* xr = x + (size_t)(rowbase + 16 * tm + lq) * 64 + quad * 8;
            #pragma unroll
            for (int half = 0; half < 2; ++half) {
                float4v f0 = *(const float4v*)(xr + 32 * half);
                float4v f1 = *(const float4v*)(xr + 32 * half + 4);
                union { short8 s; unsigned int u[4]; } p;
                p.u[0] = packbf2(f0[0], f0[1]);
                p.u[1] = packbf2(f0[2], f0[3]);
                p.u[2] = packbf2(f1[0], f1[1]);
                p.u[3] = packbf2(f1[2], f1[3]);
                xf[tm][half] = p.s;
            }
        }
    }

    #pragma unroll 1
    for (int idx = 0; idx < 4; ++idx) {
        const int net = g * 4 + idx;

        if (net == 0) {
            // constant network: uniform scalar; each thread fills col 0 of its row
            float s = 0.f, tr = 0.f;
            #pragma unroll 8
            for (int j = 0; j < 64; ++j) {
                float h = fmaxf(w0[j] + b0[j], 0.f);
                s  += h * v0[2 * j];
                tr += h * v0[2 * j + 1];
            }
            s += c0[0];
            tr += c0[1];
            s = fminf(fmaxf(s, -5.f), 5.f);
            sOut[0][t][0] = s;
            sOut[1][t][0] = tr;
            continue;
        }

        const int kn = net - 1;
        const char* pA1 = frag + FR_A1 + kn * 8192 + lane * 32;
        const char* pA2 = frag + FR_A2 + kn * 8192 + lane * 128;
        const char* pA3 = frag + FR_A3 + kn * 2048 + lane * 32;

        // ---- R8/R10-verified inner body, tm=4 ----
        float4v acc2[4][4];
        #pragma unroll
        for (int th = 0; th < 4; ++th) {
            short8 a10 = *(const short8*)(pA1 + th * 2048);
            short8 a11 = *(const short8*)(pA1 + th * 2048 + 16);
            float4v bias1 = *(const float4v*)(B1 + kn * 64 + quad * 4 + 16 * th);
            short4v bf1[4];
            #pragma unroll
            for (int tm = 0; tm < 4; ++tm) {
                float4v acc1;
                acc1 = __builtin_amdgcn_mfma_f32_16x16x32_bf16(a10, xf[tm][0], bias1, 0, 0, 0);
                acc1 = __builtin_amdgcn_mfma_f32_16x16x32_bf16(a11, xf[tm][1], acc1, 0, 0, 0);
                union { short4v s; unsigned int u[2]; } pk;
                pk.u[0] = cvt_relu(acc1[0], acc1[1]);
                pk.u[1] = cvt_relu(acc1[2], acc1[3]);
                bf1[tm] = pk.s;
            }
            if (th == 0) {
                #pragma unroll
                for (int tg = 0; tg < 4; ++tg) {
                    short4v a2 = *(const short4v*)(pA2 + tg * 32);
                    float4v bias2 = *(const float4v*)(B2 + kn * 64 + quad * 4 + 16 * tg);
                    #pragma unroll
                    for (int tm = 0; tm < 4; ++tm)
                        acc2[tg][tm] = __builtin_amdgcn_mfma_f32_16x16x16bf16_1k(a2, bf1[tm], bias2, 0, 0, 0);
                }
            } else {
                #pragma unroll
                for (int tg = 0; tg < 4; ++tg) {
                    short4v a2 = *(const short4v*)(pA2 + tg * 32 + th * 8);
                    #pragma unroll
                    for (int tm = 0; tm < 4; ++tm)
                        acc2[tg][tm] = __builtin_amdgcn_mfma_f32_16x16x16bf16_1k(a2, bf1[tm], acc2[tg][tm], 0, 0, 0);
                }
            }
        }

        // ---- layer 3 ----
        float4v c3v;
        c3v[0] = B3[kn * 2]; c3v[1] = B3[kn * 2 + 1]; c3v[2] = 0.f; c3v[3] = 0.f;
        float4v acc3[4];
        #pragma unroll
        for (int tg = 0; tg < 4; ++tg) {
            short4v a3 = *(const short4v*)(pA3 + tg * 8);
            #pragma unroll
            for (int tm = 0; tm < 4; ++tm) {
                union { short4v s; unsigned int u[2]; } pk;
                pk.u[0] = cvt_relu(acc2[tg][tm][0], acc2[tg][tm][1]);
                pk.u[1] = cvt_relu(acc2[tg][tm][2], acc2[tg][tm][3]);
                acc3[tm] = __builtin_amdgcn_mfma_f32_16x16x16bf16_1k(a3, pk.s, (tg == 0) ? c3v : acc3[tm], 0, 0, 0);
            }
        }

        // ---- epilogue -> LDS tile (col = idx) ----
        if (quad == 0) {
            #pragma unroll
            for (int tm = 0; tm < 4; ++tm) {
                const int lr = w * 64 + 16 * tm + lq;
                sOut[0][lr][idx] = fminf(fmaxf(acc3[tm][0], -5.f), 5.f);
                sOut[1][lr][idx] = acc3[tm][1];
            }
        }
    }

    __syncthreads();

    // ---- dense write-out: thread t = row; both outputs, 4 cols = 16B each ----
    {
        const int row = t;                       // 0..255
        const size_t grow = (size_t)chunk * 256 + row;
        #pragma unroll
        for (int o = 0; o < 2; ++o) {
            float4v v4;
            #pragma unroll
            for (int j = 0; j < 4; ++j) v4[j] = sOut[o][row][j];
            float* dst = out + ((size_t)o * BATCH + grow) * 64 + 4 * g;
            *(float4v*)(dst) = v4;
        }
    }
}

// ---------------- fallback (R4, verified): used only if ws_size < FR_SIZE ----------------
#define WPAD 72
__global__ __launch_bounds__(256) void arnet_fallback(
    const float* __restrict__ x, const float* __restrict__ w0, const float* __restrict__ b0,
    const float* __restrict__ v0, const float* __restrict__ c0,
    const float* __restrict__ W1, const float* __restrict__ B1,
    const float* __restrict__ W2, const float* __restrict__ B2,
    const float* __restrict__ W3, const float* __restrict__ B3,
    float* __restrict__ out)
{
    const int bi = blockIdx.x;
    const int net = bi >> 5;
    const int tile = bi & 31;
    const int t = threadIdx.x;
    if (net == 0) {
        float s = 0.f, tr = 0.f;
        for (int j = 0; j < 64; ++j) {
            float h = fmaxf(w0[j] + b0[j], 0.f);
            s += h * v0[2 * j]; tr += h * v0[2 * j + 1];
        }
        s += c0[0]; tr += c0[1];
        s = fminf(fmaxf(s, -5.f), 5.f);
        const size_t r0 = (size_t)tile * 512;
        out[(r0 + t) * 64] = s; out[(size_t)BATCH * 64 + (r0 + t) * 64] = tr;
        out[(r0 + 256 + t) * 64] = s; out[(size_t)BATCH * 64 + (r0 + 256 + t) * 64] = tr;
        return;
    }
    __shared__ unsigned short sW1T[64 * WPAD];
    __shared__ unsigned short sW2T[64 * WPAD];
    __shared__ unsigned short sW3T[2 * 64];
    __shared__ float sB1[64];
    __shared__ float sB2[64];
    const int kn = net - 1;
    {
        const int hb = (t & 15) * 4, jb = (t >> 4) * 4;
        const float* src1 = W1 + kn * 4096;
        const float* src2 = W2 + kn * 4096;
        float4v a[4], b[4];
        for (int jj = 0; jj < 4; ++jj) {
            a[jj] = *(const float4v*)(src1 + (jb + jj) * 64 + hb);
            if (jb + jj >= net) a[jj] = (float4v)0.f;
            b[jj] = *(const float4v*)(src2 + (jb + jj) * 64 + hb);
        }
        for (int hh = 0; hh < 4; ++hh) {
            ushort4v ra, rb;
            for (int jj = 0; jj < 4; ++jj) { ra[jj] = f2bf(a[jj][hh]); rb[jj] = f2bf(b[jj][hh]); }
            *(ushort4v*)(&sW1T[(hb + hh) * WPAD + jb]) = ra;
            *(ushort4v*)(&sW2T[(hb + hh) * WPAD + jb]) = rb;
        }
    }
    if (t < 64) {
        sW3T[t] = f2bf(W3[kn * 128 + t * 2]);
        sW3T[64 + t] = f2bf(W3[kn * 128 + t * 2 + 1]);
        sB1[t] = B1[kn * 64 + t];
        sB2[t] = B2[kn * 64 + t];
    }
    const float b30 = B3[kn * 2], b31 = B3[kn * 2 + 1];
    __syncthreads();
    const int lane = t & 63, w = t >> 6, lq = lane & 15, quad = lane >> 4;
    for (int pass = 0; pass < 2; ++pass) {
        const int rowbase = tile * 512 + pass * 256 + w * 64;
        short8 xf[4][2];
        for (int tm = 0; tm < 4; ++tm) {
            const float* xr = x + (size_t)(rowbase + 16 * tm + lq) * 64 + quad * 8;
            for (int half = 0; half < 2; ++half) {
                float4v f0 = *(const float4v*)(xr + 32 * half);
                float4v f1 = *(const float4v*)(xr + 32 * half + 4);
                union { short8 s; unsigned int u[4]; } p;
                p.u[0] = packbf2(f0[0], f0[1]); p.u[1] = packbf2(f0[2], f0[3]);
                p.u[2] = packbf2(f1[0], f1[1]); p.u[3] = packbf2(f1[2], f1[3]);
                xf[tm][half] = p.s;
            }
        }
        float4v acc2[4][4];
        for (int tg = 0; tg < 4; ++tg) {
            float4v bias2 = *(const float4v*)(&sB2[quad * 4 + 16 * tg]);
            for (int tm = 0; tm < 4; ++tm) acc2[tg][tm] = bias2;
        }
        for (int th = 0; th < 4; ++th) {
            float4v bias1 = *(const float4v*)(&sB1[quad * 4 + 16 * th]);
            short8 a10 = *(const short8*)(&sW1T[(lq + 16 * th) * WPAD + quad * 8]);
            short8 a11 = *(const short8*)(&sW1T[(lq + 16 * th) * WPAD + quad * 8 + 32]);
            float4v acc1[4];
            for (int tm = 0; tm < 4; ++tm) {
                acc1[tm] = bias1;
                acc1[tm] = __builtin_amdgcn_mfma_f32_16x16x32_bf16(a10, xf[tm][0], acc1[tm], 0, 0, 0);
                acc1[tm] = __builtin_amdgcn_mfma_f32_16x16x32_bf16(a11, xf[tm][1], acc1[tm], 0, 0, 0);
            }
            short4v bf1[4];
            for (int tm = 0; tm < 4; ++tm) {
                union { short4v s; unsigned int u[2]; } pk;
                pk.u[0] = cvt_relu(acc1[tm][0], acc1[tm][1]);
                pk.u[1] = cvt_relu(acc1[tm][2], acc1[tm][3]);
                bf1[tm] = pk.s;
            }
            for (int tg = 0; tg < 4; ++tg) {
                short4v a2 = *(const short4v*)(&sW2T[(lq + 16 * tg) * WPAD + quad * 4 + 16 * th]);
                for (int tm = 0; tm < 4; ++tm)
                    acc2[tg][tm] = __builtin_amdgcn_mfma_f32_16x16x16bf16_1k(a2, bf1[tm], acc2[tg][tm], 0, 0, 0);
            }
        }
        float4v acc3[4];
        for (int tm = 0; tm < 4; ++tm) { acc3[tm][0] = b30; acc3[tm][1] = b31; acc3[tm][2] = 0.f; acc3[tm][3] = 0.f; }
        for (int tg = 0; tg < 4; ++tg) {
            short4v a3 = (short4v)0;
            if (lq < 2) a3 = *(const short4v*)(&sW3T[lq * 64 + quad * 4 + 16 * tg]);
            for (int tm = 0; tm < 4; ++tm) {
                union { short4v s; unsigned int u[2]; } pk;
                pk.u[0] = cvt_relu(acc2[tg][tm][0], acc2[tg][tm][1]);
                pk.u[1] = cvt_relu(acc2[tg][tm][2], acc2[tg][tm][3]);
                acc3[tm] = __builtin_amdgcn_mfma_f32_16x16x16bf16_1k(a3, pk.s, acc3[tm], 0, 0, 0);
            }
        }
        if (quad == 0) {
            for (int tm = 0; tm < 4; ++tm) {
                const size_t r = (size_t)(rowbase + 16 * tm + lq);
                out[r * 64 + net] = fminf(fmaxf(acc3[tm][0], -5.f), 5.f);
                out[(size_t)BATCH * 64 + r * 64 + net] = acc3[tm][1];
            }
        }
    }
}

extern "C" void kernel_launch(void* const* d_in, const int* in_sizes, int n_in,
                              void* d_out, int out_size, void* d_ws, size_t ws_size,
                              hipStream_t stream) {
    const float* x  = (const float*)d_in[0];
    const float* w0 = (const float*)d_in[1];
    const float* b0 = (const float*)d_in[2];
    const float* v0 = (const float*)d_in[3];
    const float* c0 = (const float*)d_in[4];
    const float* W1 = (const float*)d_in[5];
    const float* B1 = (const float*)d_in[6];
    const float* W2 = (const float*)d_in[7];
    const float* B2 = (const float*)d_in[8];
    const float* W3 = (const float*)d_in[9];
    const float* B3 = (const float*)d_in[10];
    float* out = (float*)d_out;
    char* ws = (char*)d_ws;

    const dim3 blk(256);

    if (ws_size >= FR_SIZE + XBF_SIZE) {
        char* xbf = ws + FR_SIZE;
        setup_kernel<<<dim3(63 + 256), blk, 0, stream>>>(x, W1, W2, W3, ws, xbf);
        arnet_main4<true><<<dim3(1024), blk, 0, stream>>>(
            x, xbf, ws, w0, b0, v0, c0, B1, B2, B3, out);
    } else if (ws_size >= FR_SIZE) {
        setup_kernel<<<dim3(63), blk, 0, stream>>>(x, W1, W2, W3, ws, nullptr);
        arnet_main4<false><<<dim3(1024), blk, 0, stream>>>(
            x, nullptr, ws, w0, b0, v0, c0, B1, B2, B3, out);
    } else {
        arnet_fallback<<<dim3(64 * 32), blk, 0, stream>>>(
            x, w0, b0, v0, c0, W1, B1, W2, B2, W3, B3, out);
    }
}

// Round 13
// 119.991 us; speedup vs baseline: 1.5306x; 1.5306x over previous
//
#include <hip/hip_runtime.h>
#include <hip/hip_bf16.h>

#define BATCH 16384

typedef __attribute__((ext_vector_type(8))) short short8;
typedef __attribute__((ext_vector_type(4))) short short4v;
typedef __attribute__((ext_vector_type(2))) short sshort2;
typedef __attribute__((ext_vector_type(8))) unsigned short ushort8;
typedef __attribute__((ext_vector_type(4))) unsigned short ushort4v;
typedef __attribute__((ext_vector_type(4))) float float4v;

// ---- d_ws layout (bytes) ----
// frags: A1 [63][th:4][lane:64][32B] | A2 [63][lane:64][tg:4][th:4][8B] | A3 [63][lane:64][tg:4][8B]
#define FR_A1      0u
#define FR_A2      516096u
#define FR_A3      1032192u
#define FR_SIZE    1161216u
#define XBF_SIZE   2097152u     // x as bf16 [16384][64]

__device__ __forceinline__ unsigned int packbf2(float a, float b) {
#if __has_builtin(__builtin_amdgcn_cvt_pk_bf16_f32)
    typedef __attribute__((ext_vector_type(2))) __bf16 bf2_t;
    union { bf2_t h; unsigned int u; } v;
    v.h = __builtin_amdgcn_cvt_pk_bf16_f32(a, b);
    return v.u;
#else
    union { __hip_bfloat162 h; unsigned int u; } v;
    v.h = __float22bfloat162_rn(make_float2(a, b));
    return v.u;
#endif
}
// packed relu on two bf16 halves: i16 max with 0 (valid: bf16 neg <=> i16 neg; no NaNs here)
__device__ __forceinline__ unsigned int relu_pk(unsigned int u) {
#if __has_builtin(__builtin_elementwise_max)
    union { sshort2 s; unsigned int w; } v; v.w = u;
    v.s = __builtin_elementwise_max(v.s, (sshort2)0);
    return v.w;
#else
    unsigned int lo = (u & 0x8000u) ? 0u : (u & 0xFFFFu);
    unsigned int hi = (u & 0x80000000u) ? 0u : (u & 0xFFFF0000u);
    return lo | hi;
#endif
}
__device__ __forceinline__ unsigned int cvt_relu(float a, float b) {
    return relu_pk(packbf2(a, b));
}
__device__ __forceinline__ unsigned short f2bf(float a) {
    union { __hip_bfloat16 h; unsigned short u; } v;
    v.h = __float2bfloat16(a);
    return v.u;
}

// ---------------- setup: fused weight-fragment prep (blocks 0..62) + x cvt (blocks 63..318) ----------------
__global__ __launch_bounds__(256) void setup_kernel(
    const float* __restrict__ x,
    const float* __restrict__ W1,  // [63,64,64] [d][h]
    const float* __restrict__ W2,  // [63,64,64] [h][g]
    const float* __restrict__ W3,  // [63,64,2]  [g][o]
    char* __restrict__ frag,
    char* __restrict__ xbf)        // may be null when grid==63
{
    const int b = blockIdx.x;
    const int t = threadIdx.x;

    if (b >= 63) {
        const int idx = (b - 63) * 256 + t;          // 0..65535, 16 floats each
        const float* xp = x + (size_t)idx * 16;
        char* dst = xbf + (size_t)idx * 32;
        #pragma unroll
        for (int h = 0; h < 2; ++h) {
            float4v f0 = *(const float4v*)(xp + h * 8);
            float4v f1 = *(const float4v*)(xp + h * 8 + 4);
            union { ushort8 s; unsigned int u[4]; } p;
            p.u[0] = packbf2(f0[0], f0[1]);
            p.u[1] = packbf2(f0[2], f0[3]);
            p.u[2] = packbf2(f1[0], f1[1]);
            p.u[3] = packbf2(f1[2], f1[3]);
            *(ushort8*)(dst + h * 16) = p.s;
        }
        return;
    }

    const int kn   = b;
    const int net  = kn + 1;
    const int lane = t & 63;
    const int grp  = t >> 6;       // th (A1) / tg (A2, A3)
    const int lq   = lane & 15;
    const int quad = lane >> 4;

    // A1: A[m=h=lq+16*th][k=d=quad*8+j (a10) / +32 (a11)], masked d < net
    {
        const int h = lq + 16 * grp;
        ushort8 a10, a11;
        #pragma unroll
        for (int j = 0; j < 8; ++j) {
            const int d0 = quad * 8 + j;
            const int d1 = d0 + 32;
            a10[j] = (d0 < net) ? f2bf(W1[kn * 4096 + d0 * 64 + h]) : (unsigned short)0;
            a11[j] = (d1 < net) ? f2bf(W1[kn * 4096 + d1 * 64 + h]) : (unsigned short)0;
        }
        char* dst = frag + FR_A1 + kn * 8192 + grp * 2048 + lane * 32;
        *(ushort8*)(dst)      = a10;
        *(ushort8*)(dst + 16) = a11;
    }

    // A2 (_1k): A[m=g=lq+16*tg][k=h=quad*4+16*th+i]
    {
        const int g = lq + 16 * grp;
        #pragma unroll
        for (int th = 0; th < 4; ++th) {
            ushort4v v;
            #pragma unroll
            for (int i = 0; i < 4; ++i) {
                const int h = quad * 4 + 16 * th + i;
                v[i] = f2bf(W2[kn * 4096 + h * 64 + g]);
            }
            *(ushort4v*)(frag + FR_A2 + kn * 8192 + lane * 128 + grp * 32 + th * 8) = v;
        }
    }

    // A3 (_1k): A[m=o=lq (0/1)][k=g=quad*4+16*tg+i], rows >= 2 zero
    {
        ushort4v v;
        #pragma unroll
        for (int i = 0; i < 4; ++i) {
            const int g = quad * 4 + 16 * grp + i;
            v[i] = (lq < 2) ? f2bf(W3[kn * 128 + g * 2 + lq]) : (unsigned short)0;
        }
        *(ushort4v*)(frag + FR_A3 + kn * 2048 + lane * 32 + grp * 8) = v;
    }
}

// ---------------- main: block = 256-row chunk x 4-net group; 64 rows/wave (tm=4); 12 waves/CU ----------------
// grid 1024: chunk = bi & 63, group g = bi >> 6 (0..15). Line-sharing groups differ by 64 in bi -> same XCD.
// __launch_bounds__(256,3): VGPR budget 170 -> tm=4 body (~84-110 VGPR) fits with ZERO spill
// (R12's (256,4) capped at 128 -> 350 MB scratch traffic; R10's (256,2) left occupancy on the table).
template <bool XBF>
__global__ __launch_bounds__(256, 3) void arnet_main4(
    const float* __restrict__ x,
    const char* __restrict__ xbf,
    const char* __restrict__ frag,
    const float* __restrict__ w0, const float* __restrict__ b0,
    const float* __restrict__ v0, const float* __restrict__ c0,
    const float* __restrict__ B1, const float* __restrict__ B2,
    const float* __restrict__ B3,
    float* __restrict__ out)
{
    const int bi    = blockIdx.x;        // 0..1023
    const int chunk = bi & 63;           // 256-row chunk
    const int g     = bi >> 6;           // net group: nets 4g .. 4g+3
    const int t     = threadIdx.x;

    const int lane = t & 63;
    const int w    = t >> 6;
    const int lq   = lane & 15;
    const int quad = lane >> 4;

    __shared__ float sOut[2][256][5];    // pad 5: write conflict-free; 10 KB

    const int rowbase = chunk * 256 + w * 64;

    // ---- load x fragments ONCE (64 rows/wave), reuse for all 4 nets ----
    short8 xf[4][2];
    #pragma unroll
    for (int tm = 0; tm < 4; ++tm) {
        if (XBF) {
            const char* base = xbf + (size_t)(rowbase + 16 * tm + lq) * 128 + quad * 16;
            xf[tm][0] = *(const short8*)(base);
            xf[tm][1] = *(const short8*)(base + 64);
        } else {
            const float* xr = x + (size_t)(rowbase + 16 * tm + lq) * 64 + quad * 8;
            #pragma unroll
            for (int half = 0; half < 2; ++half) {
                float4v f0 = *(const float4v*)(xr + 32 * half);
                float4v f1 = *(const float4v*)(xr + 32 * half + 4);
                union { short8 s; unsigned int u[4]; } p;
                p.u[0] = packbf2(f0[0], f0[1]);
                p.u[1] = packbf2(f0[2], f0[3]);
                p.u[2] = packbf2(f1[0], f1[1]);
                p.u[3] = packbf2(f1[2], f1[3]);
                xf[tm][half] = p.s;
            }
        }
    }

    #pragma unroll 1
    for (int idx = 0; idx < 4; ++idx) {
        const int net = g * 4 + idx;

        if (net == 0) {
            // constant network: uniform scalar; each thread fills col 0 of its row
            float s = 0.f, tr = 0.f;
            #pragma unroll 8
            for (int j = 0; j < 64; ++j) {
                float h = fmaxf(w0[j] + b0[j], 0.f);
                s  += h * v0[2 * j];
                tr += h * v0[2 * j + 1];
            }
            s += c0[0];
            tr += c0[1];
            s = fminf(fmaxf(s, -5.f), 5.f);
            sOut[0][t][0] = s;
            sOut[1][t][0] = tr;
            continue;
        }

        const int kn = net - 1;
        const char* pA1 = frag + FR_A1 + kn * 8192 + lane * 32;
        const char* pA2 = frag + FR_A2 + kn * 8192 + lane * 128;
        const char* pA3 = frag + FR_A3 + kn * 2048 + lane * 32;

        // ---- R8/R10-verified inner body, tm=4 ----
        float4v acc2[4][4];
        #pragma unroll
        for (int th = 0; th < 4; ++th) {
            short8 a10 = *(const short8*)(pA1 + th * 2048);
            short8 a11 = *(const short8*)(pA1 + th * 2048 + 16);
            float4v bias1 = *(const float4v*)(B1 + kn * 64 + quad * 4 + 16 * th);
            short4v bf1[4];
            #pragma unroll
            for (int tm = 0; tm < 4; ++tm) {
                float4v acc1;
                acc1 = __builtin_amdgcn_mfma_f32_16x16x32_bf16(a10, xf[tm][0], bias1, 0, 0, 0);
                acc1 = __builtin_amdgcn_mfma_f32_16x16x32_bf16(a11, xf[tm][1], acc1, 0, 0, 0);
                union { short4v s; unsigned int u[2]; } pk;
                pk.u[0] = cvt_relu(acc1[0], acc1[1]);
                pk.u[1] = cvt_relu(acc1[2], acc1[3]);
                bf1[tm] = pk.s;
            }
            if (th == 0) {
                #pragma unroll
                for (int tg = 0; tg < 4; ++tg) {
                    short4v a2 = *(const short4v*)(pA2 + tg * 32);
                    float4v bias2 = *(const float4v*)(B2 + kn * 64 + quad * 4 + 16 * tg);
                    #pragma unroll
                    for (int tm = 0; tm < 4; ++tm)
                        acc2[tg][tm] = __builtin_amdgcn_mfma_f32_16x16x16bf16_1k(a2, bf1[tm], bias2, 0, 0, 0);
                }
            } else {
                #pragma unroll
                for (int tg = 0; tg < 4; ++tg) {
                    short4v a2 = *(const short4v*)(pA2 + tg * 32 + th * 8);
                    #pragma unroll
                    for (int tm = 0; tm < 4; ++tm)
                        acc2[tg][tm] = __builtin_amdgcn_mfma_f32_16x16x16bf16_1k(a2, bf1[tm], acc2[tg][tm], 0, 0, 0);
                }
            }
        }

        // ---- layer 3 ----
        float4v c3v;
        c3v[0] = B3[kn * 2]; c3v[1] = B3[kn * 2 + 1]; c3v[2] = 0.f; c3v[3] = 0.f;
        float4v acc3[4];
        #pragma unroll
        for (int tg = 0; tg < 4; ++tg) {
            short4v a3 = *(const short4v*)(pA3 + tg * 8);
            #pragma unroll
            for (int tm = 0; tm < 4; ++tm) {
                union { short4v s; unsigned int u[2]; } pk;
                pk.u[0] = cvt_relu(acc2[tg][tm][0], acc2[tg][tm][1]);
                pk.u[1] = cvt_relu(acc2[tg][tm][2], acc2[tg][tm][3]);
                acc3[tm] = __builtin_amdgcn_mfma_f32_16x16x16bf16_1k(a3, pk.s, (tg == 0) ? c3v : acc3[tm], 0, 0, 0);
            }
        }

        // ---- epilogue -> LDS tile (col = idx) ----
        if (quad == 0) {
            #pragma unroll
            for (int tm = 0; tm < 4; ++tm) {
                const int lr = w * 64 + 16 * tm + lq;
                sOut[0][lr][idx] = fminf(fmaxf(acc3[tm][0], -5.f), 5.f);
                sOut[1][lr][idx] = acc3[tm][1];
            }
        }
    }

    __syncthreads();

    // ---- dense write-out: thread t = row; both outputs, 4 cols = 16B each ----
    {
        const int row = t;                       // 0..255
        const size_t grow = (size_t)chunk * 256 + row;
        #pragma unroll
        for (int o = 0; o < 2; ++o) {
            float4v v4;
            #pragma unroll
            for (int j = 0; j < 4; ++j) v4[j] = sOut[o][row][j];
            float* dst = out + ((size_t)o * BATCH + grow) * 64 + 4 * g;
            *(float4v*)(dst) = v4;
        }
    }
}

// ---------------- fallback (R4, verified): used only if ws_size < FR_SIZE ----------------
#define WPAD 72
__global__ __launch_bounds__(256) void arnet_fallback(
    const float* __restrict__ x, const float* __restrict__ w0, const float* __restrict__ b0,
    const float* __restrict__ v0, const float* __restrict__ c0,
    const float* __restrict__ W1, const float* __restrict__ B1,
    const float* __restrict__ W2, const float* __restrict__ B2,
    const float* __restrict__ W3, const float* __restrict__ B3,
    float* __restrict__ out)
{
    const int bi = blockIdx.x;
    const int net = bi >> 5;
    const int tile = bi & 31;
    const int t = threadIdx.x;
    if (net == 0) {
        float s = 0.f, tr = 0.f;
        for (int j = 0; j < 64; ++j) {
            float h = fmaxf(w0[j] + b0[j], 0.f);
            s += h * v0[2 * j]; tr += h * v0[2 * j + 1];
        }
        s += c0[0]; tr += c0[1];
        s = fminf(fmaxf(s, -5.f), 5.f);
        const size_t r0 = (size_t)tile * 512;
        out[(r0 + t) * 64] = s; out[(size_t)BATCH * 64 + (r0 + t) * 64] = tr;
        out[(r0 + 256 + t) * 64] = s; out[(size_t)BATCH * 64 + (r0 + 256 + t) * 64] = tr;
        return;
    }
    __shared__ unsigned short sW1T[64 * WPAD];
    __shared__ unsigned short sW2T[64 * WPAD];
    __shared__ unsigned short sW3T[2 * 64];
    __shared__ float sB1[64];
    __shared__ float sB2[64];
    const int kn = net - 1;
    {
        const int hb = (t & 15) * 4, jb = (t >> 4) * 4;
        const float* src1 = W1 + kn * 4096;
        const float* src2 = W2 + kn * 4096;
        float4v a[4], b[4];
        for (int jj = 0; jj < 4; ++jj) {
            a[jj] = *(const float4v*)(src1 + (jb + jj) * 64 + hb);
            if (jb + jj >= net) a[jj] = (float4v)0.f;
            b[jj] = *(const float4v*)(src2 + (jb + jj) * 64 + hb);
        }
        for (int hh = 0; hh < 4; ++hh) {
            ushort4v ra, rb;
            for (int jj = 0; jj < 4; ++jj) { ra[jj] = f2bf(a[jj][hh]); rb[jj] = f2bf(b[jj][hh]); }
            *(ushort4v*)(&sW1T[(hb + hh) * WPAD + jb]) = ra;
            *(ushort4v*)(&sW2T[(hb + hh) * WPAD + jb]) = rb;
        }
    }
    if (t < 64) {
        sW3T[t] = f2bf(W3[kn * 128 + t * 2]);
        sW3T[64 + t] = f2bf(W3[kn * 128 + t * 2 + 1]);
        sB1[t] = B1[kn * 64 + t];
        sB2[t] = B2[kn * 64 + t];
    }
    const float b30 = B3[kn * 2], b31 = B3[kn * 2 + 1];
    __syncthreads();
    const int lane = t & 63, w = t >> 6, lq = lane & 15, quad = lane >> 4;
    for (int pass = 0; pass < 2; ++pass) {
        const int rowbase = tile * 512 + pass * 256 + w * 64;
        short8 xf[4][2];
        for (int tm = 0; tm < 4; ++tm) {
            const float* xr = x + (size_t)(rowbase + 16 * tm + lq) * 64 + quad * 8;
            for (int half = 0; half < 2; ++half) {
                float4v f0 = *(const float4v*)(xr + 32 * half);
                float4v f1 = *(const float4v*)(xr + 32 * half + 4);
                union { short8 s; unsigned int u[4]; } p;
                p.u[0] = packbf2(f0[0], f0[1]); p.u[1] = packbf2(f0[2], f0[3]);
                p.u[2] = packbf2(f1[0], f1[1]); p.u[3] = packbf2(f1[2], f1[3]);
                xf[tm][half] = p.s;
            }
        }
        float4v acc2[4][4];
        for (int tg = 0; tg < 4; ++tg) {
            float4v bias2 = *(const float4v*)(&sB2[quad * 4 + 16 * tg]);
            for (int tm = 0; tm < 4; ++tm) acc2[tg][tm] = bias2;
        }
        for (int th = 0; th < 4; ++th) {
            float4v bias1 = *(const float4v*)(&sB1[quad * 4 + 16 * th]);
            short8 a10 = *(const short8*)(&sW1T[(lq + 16 * th) * WPAD + quad * 8]);
            short8 a11 = *(const short8*)(&sW1T[(lq + 16 * th) * WPAD + quad * 8 + 32]);
            float4v acc1[4];
            for (int tm = 0; tm < 4; ++tm) {
                acc1[tm] = bias1;
                acc1[tm] = __builtin_amdgcn_mfma_f32_16x16x32_bf16(a10, xf[tm][0], acc1[tm], 0, 0, 0);
                acc1[tm] = __builtin_amdgcn_mfma_f32_16x16x32_bf16(a11, xf[tm][1], acc1[tm], 0, 0, 0);
            }
            short4v bf1[4];
            for (int tm = 0; tm < 4; ++tm) {
                union { short4v s; unsigned int u[2]; } pk;
                pk.u[0] = cvt_relu(acc1[tm][0], acc1[tm][1]);
                pk.u[1] = cvt_relu(acc1[tm][2], acc1[tm][3]);
                bf1[tm] = pk.s;
            }
            for (int tg = 0; tg < 4; ++tg) {
                short4v a2 = *(const short4v*)(&sW2T[(lq + 16 * tg) * WPAD + quad * 4 + 16 * th]);
                for (int tm = 0; tm < 4; ++tm)
                    acc2[tg][tm] = __builtin_amdgcn_mfma_f32_16x16x16bf16_1k(a2, bf1[tm], acc2[tg][tm], 0, 0, 0);
            }
        }
        float4v acc3[4];
        for (int tm = 0; tm < 4; ++tm) { acc3[tm][0] = b30; acc3[tm][1] = b31; acc3[tm][2] = 0.f; acc3[tm][3] = 0.f; }
        for (int tg = 0; tg < 4; ++tg) {
            short4v a3 = (short4v)0;
            if (lq < 2) a3 = *(const short4v*)(&sW3T[lq * 64 + quad * 4 + 16 * tg]);
            for (int tm = 0; tm < 4; ++tm) {
                union { short4v s; unsigned int u[2]; } pk;
                pk.u[0] = cvt_relu(acc2[tg][tm][0], acc2[tg][tm][1]);
                pk.u[1] = cvt_relu(acc2[tg][tm][2], acc2[tg][tm][3]);
                acc3[tm] = __builtin_amdgcn_mfma_f32_16x16x16bf16_1k(a3, pk.s, acc3[tm], 0, 0, 0);
            }
        }
        if (quad == 0) {
            for (int tm = 0; tm < 4; ++tm) {
                const size_t r = (size_t)(rowbase + 16 * tm + lq);
                out[r * 64 + net] = fminf(fmaxf(acc3[tm][0], -5.f), 5.f);
                out[(size_t)BATCH * 64 + r * 64 + net] = acc3[tm][1];
            }
        }
    }
}

extern "C" void kernel_launch(void* const* d_in, const int* in_sizes, int n_in,
                              void* d_out, int out_size, void* d_ws, size_t ws_size,
                              hipStream_t stream) {
    const float* x  = (const float*)d_in[0];
    const float* w0 = (const float*)d_in[1];
    const float* b0 = (const float*)d_in[2];
    const float* v0 = (const float*)d_in[3];
    const float* c0 = (const float*)d_in[4];
    const float* W1 = (const float*)d_in[5];
    const float* B1 = (const float*)d_in[6];
    const float* W2 = (const float*)d_in[7];
    const float* B2 = (const float*)d_in[8];
    const float* W3 = (const float*)d_in[9];
    const float* B3 = (const float*)d_in[10];
    float* out = (float*)d_out;
    char* ws = (char*)d_ws;

    const dim3 blk(256);

    if (ws_size >= FR_SIZE + XBF_SIZE) {
        char* xbf = ws + FR_SIZE;
        setup_kernel<<<dim3(63 + 256), blk, 0, stream>>>(x, W1, W2, W3, ws, xbf);
        arnet_main4<true><<<dim3(1024), blk, 0, stream>>>(
            x, xbf, ws, w0, b0, v0, c0, B1, B2, B3, out);
    } else if (ws_size >= FR_SIZE) {
        setup_kernel<<<dim3(63), blk, 0, stream>>>(x, W1, W2, W3, ws, nullptr);
        arnet_main4<false><<<dim3(1024), blk, 0, stream>>>(
            x, nullptr, ws, w0, b0, v0, c0, B1, B2, B3, out);
    } else {
        arnet_fallback<<<dim3(64 * 32), blk, 0, stream>>>(
            x, w0, b0, v0, c0, W1, B1, W2, B2, W3, B3, out);
    }
}